// Round 1
// baseline (3852.452 us; speedup 1.0000x reference)
//
#include <hip/hip_runtime.h>
#include <hip/hip_bf16.h>
#include <math.h>

// ---------------------------------------------------------------------------
// GraphSAGE inference:
//   h1 = relu(mean_aggr(x) @ w1l + b1 + x @ w1r)
//   h2 = relu(mean_aggr(h1) @ w2l + b2 + h1 @ w2r)
//   g  = global_mean_pool(h2, batch)   [G,128]
//   out = log_softmax(g @ wf + bf)     [G,16]
// F_IN = H = 128 fixed.
// ---------------------------------------------------------------------------

#define FDIM 128

// --- edge degree count (as float) -----------------------------------------
__global__ void count_edges_k(const int* __restrict__ dst, float* __restrict__ cnt, int nE) {
    int e = blockIdx.x * blockDim.x + threadIdx.x;
    if (e < nE) atomicAdd(&cnt[dst[e]], 1.0f);
}

// cnt -> 1/max(cnt,1) in place
__global__ void recip_k(float* cnt, int n) {
    int i = blockIdx.x * blockDim.x + threadIdx.x;
    if (i < n) cnt[i] = 1.0f / fmaxf(cnt[i], 1.0f);
}

// --- scatter-add rows: msg[dst] += feat[src], 32 lanes/edge, float4/lane ---
__global__ void scatter_add_k(const float* __restrict__ feat,
                              const int* __restrict__ src,
                              const int* __restrict__ dst,
                              float* __restrict__ msg, int nE) {
    long long gid = (long long)blockIdx.x * blockDim.x + threadIdx.x;
    int lane = (int)(gid & 31);
    long long e = gid >> 5;
    if (e >= nE) return;
    int s = src[e], d = dst[e];
    float4 v = ((const float4*)(feat + (size_t)s * FDIM))[lane];
    float* o = msg + (size_t)d * FDIM + lane * 4;
    atomicAdd(o + 0, v.x);
    atomicAdd(o + 1, v.y);
    atomicAdd(o + 2, v.z);
    atomicAdd(o + 3, v.w);
}

// --- fused SAGE layer GEMM: out = relu?( (msg*rcnt) @ wl + bias + root @ wr )
// block = 128 threads (one per output column), handles 16 rows.
// NOTE: out may alias msg (layer 2): rows are staged into LDS before the
// owning block writes them back; no cross-block row sharing -> safe.
__global__ __launch_bounds__(128) void gemm_fused_k(
        const float* msg, const float* __restrict__ rcnt,
        const float* __restrict__ root,
        const float* __restrict__ wl, const float* __restrict__ bias,
        const float* __restrict__ wr,
        float* out, int n, int do_relu) {
    __shared__ float wls[FDIM * FDIM];
    __shared__ float wrs[FDIM * FDIM];
    __shared__ float arow[4][FDIM];
    __shared__ float xrow[4][FDIM];

    int tid = threadIdx.x;
    for (int i = tid; i < FDIM * FDIM; i += 128) {
        wls[i] = wl[i];
        wrs[i] = wr[i];
    }
    float b = bias[tid];
    int r0 = blockIdx.x * 16;

    for (int rg = 0; rg < 4; ++rg) {
        int rbase = r0 + rg * 4;
        __syncthreads();
        #pragma unroll
        for (int i = 0; i < 4; ++i) {
            int r = rbase + i;
            if (r < n) {
                float rc = rcnt[r];
                arow[i][tid] = msg[(size_t)r * FDIM + tid] * rc;
                xrow[i][tid] = root[(size_t)r * FDIM + tid];
            }
        }
        __syncthreads();

        float acc0 = b, acc1 = b, acc2 = b, acc3 = b;
        for (int k = 0; k < FDIM; ++k) {
            float wlv = wls[k * FDIM + tid];
            float wrv = wrs[k * FDIM + tid];
            acc0 += arow[0][k] * wlv + xrow[0][k] * wrv;
            acc1 += arow[1][k] * wlv + xrow[1][k] * wrv;
            acc2 += arow[2][k] * wlv + xrow[2][k] * wrv;
            acc3 += arow[3][k] * wlv + xrow[3][k] * wrv;
        }

        float acc[4] = {acc0, acc1, acc2, acc3};
        #pragma unroll
        for (int i = 0; i < 4; ++i) {
            int r = rbase + i;
            if (r < n) {
                float v = acc[i];
                if (do_relu) v = fmaxf(v, 0.0f);
                out[(size_t)r * FDIM + tid] = v;
            }
        }
    }
}

// --- global mean pool accumulation ----------------------------------------
__global__ void pool_k(const float* __restrict__ h, const int* __restrict__ batch,
                       float* __restrict__ gsum, float* __restrict__ gcnt, int n) {
    long long gid = (long long)blockIdx.x * blockDim.x + threadIdx.x;
    int lane = (int)(gid & 31);
    long long node = gid >> 5;
    if (node >= n) return;
    int g = batch[node];
    float4 v = ((const float4*)(h + (size_t)node * FDIM))[lane];
    float* o = gsum + (size_t)g * FDIM + lane * 4;
    atomicAdd(o + 0, v.x);
    atomicAdd(o + 1, v.y);
    atomicAdd(o + 2, v.z);
    atomicAdd(o + 3, v.w);
    if (lane == 0) atomicAdd(&gcnt[g], 1.0f);
}

// --- head: logits = g @ wf + bf ; log_softmax -----------------------------
__global__ __launch_bounds__(64) void head_k(const float* __restrict__ gsum,
                                             const float* __restrict__ gcnt,
                                             const float* __restrict__ wf,
                                             const float* __restrict__ bf,
                                             float* __restrict__ out, int nG) {
    int g = blockIdx.x;
    if (g >= nG) return;
    __shared__ float row[FDIM];
    int tid = threadIdx.x;
    float inv = 1.0f / fmaxf(gcnt[g], 1.0f);
    row[tid] = gsum[(size_t)g * FDIM + tid] * inv;
    row[tid + 64] = gsum[(size_t)g * FDIM + 64 + tid] * inv;
    __syncthreads();

    float logit = -1e30f;
    if (tid < 16) {
        logit = bf[tid];
        for (int k = 0; k < FDIM; ++k) logit += row[k] * wf[k * 16 + tid];
    }
    // reduce over lanes 0..15 (xor masks < 16 keep the group closed)
    float m = logit;
    for (int off = 8; off >= 1; off >>= 1) m = fmaxf(m, __shfl_xor(m, off, 64));
    float e = (tid < 16) ? expf(logit - m) : 0.0f;
    float s = e;
    for (int off = 8; off >= 1; off >>= 1) s += __shfl_xor(s, off, 64);
    if (tid < 16) out[(size_t)g * 16 + tid] = logit - m - logf(s);
}

extern "C" void kernel_launch(void* const* d_in, const int* in_sizes, int n_in,
                              void* d_out, int out_size, void* d_ws, size_t ws_size,
                              hipStream_t stream) {
    const float* x    = (const float*)d_in[0];
    const int*   ei   = (const int*)d_in[1];
    const int*   batch= (const int*)d_in[2];
    const float* w1l  = (const float*)d_in[3];
    const float* b1   = (const float*)d_in[4];
    const float* w1r  = (const float*)d_in[5];
    const float* w2l  = (const float*)d_in[6];
    const float* b2   = (const float*)d_in[7];
    const float* w2r  = (const float*)d_in[8];
    const float* wf   = (const float*)d_in[9];
    const float* bf   = (const float*)d_in[10];
    float* out = (float*)d_out;

    const int N = in_sizes[0] / FDIM;
    const int E = in_sizes[1] / 2;
    const int G = out_size / 16;
    const int* src = ei;
    const int* dst = ei + E;

    // workspace layout (bytes)
    char* ws = (char*)d_ws;
    size_t msg_b  = (size_t)N * FDIM * sizeof(float);  // also reused as h2
    float* msg  = (float*)(ws);
    float* h1   = (float*)(ws + msg_b);
    float* rcnt = (float*)(ws + 2 * msg_b);
    float* gsum = (float*)(ws + 2 * msg_b + ((size_t)N * sizeof(float) + 255 & ~(size_t)255));
    float* gcnt = gsum + (size_t)G * FDIM;

    // --- zero accumulators (every call: determinism) ---
    hipMemsetAsync(msg, 0, msg_b, stream);
    hipMemsetAsync(rcnt, 0, (size_t)N * sizeof(float), stream);
    hipMemsetAsync(gsum, 0, ((size_t)G * FDIM + G) * sizeof(float), stream);

    // --- degree counts (shared by both layers) ---
    count_edges_k<<<(E + 255) / 256, 256, 0, stream>>>(dst, rcnt, E);
    recip_k<<<(N + 255) / 256, 256, 0, stream>>>(rcnt, N);

    // --- layer 1 ---
    {
        long long t = (long long)E * 32;
        scatter_add_k<<<(unsigned)((t + 255) / 256), 256, 0, stream>>>(x, src, dst, msg, E);
    }
    gemm_fused_k<<<(N + 15) / 16, 128, 0, stream>>>(msg, rcnt, x, w1l, b1, w1r, h1, N, 1);

    // --- layer 2 ---
    hipMemsetAsync(msg, 0, msg_b, stream);
    {
        long long t = (long long)E * 32;
        scatter_add_k<<<(unsigned)((t + 255) / 256), 256, 0, stream>>>(h1, src, dst, msg, E);
    }
    // out aliases msg: rows staged into LDS before writeback, block-private rows
    gemm_fused_k<<<(N + 15) / 16, 128, 0, stream>>>(msg, rcnt, h1, w2l, b2, w2r, msg, N, 1);

    // --- global mean pool ---
    {
        long long t = (long long)N * 32;
        pool_k<<<(unsigned)((t + 255) / 256), 256, 0, stream>>>(msg, batch, gsum, gcnt, N);
    }

    // --- head ---
    head_k<<<G, 64, 0, stream>>>(gsum, gcnt, wf, bf, out, G);
}

// Round 2
// 725.211 us; speedup vs baseline: 5.3122x; 5.3122x over previous
//
#include <hip/hip_runtime.h>
#include <hip/hip_bf16.h>
#include <math.h>

// ---------------------------------------------------------------------------
// GraphSAGE inference:
//   h1 = relu(mean_aggr(x) @ w1l + b1 + x @ w1r)
//   h2 = relu(mean_aggr(h1) @ w2l + b2 + h1 @ w2r)
//   g  = global_mean_pool(h2, batch)   [G,128]  (batch is SORTED)
//   out = log_softmax(g @ wf + bf)     [G,16]
// F_IN = H = 128 fixed.
// R1: scatter-atomics -> device-built CSR + gather (atomics were 70% of time)
// ---------------------------------------------------------------------------

#define FDIM 128

// --- CSR build -------------------------------------------------------------
__global__ void deg_count_k(const int* __restrict__ dst, int* __restrict__ deg, int nE) {
    int e = blockIdx.x * blockDim.x + threadIdx.x;
    if (e < nE) atomicAdd(&deg[dst[e]], 1);
}

// per-256-block exclusive scan; block sums out
__global__ __launch_bounds__(256) void scan1_k(const int* __restrict__ deg,
                                               int* __restrict__ rowstart,
                                               int* __restrict__ bsum, int n) {
    __shared__ int s[256];
    int tid = threadIdx.x;
    int i = blockIdx.x * 256 + tid;
    int v = (i < n) ? deg[i] : 0;
    s[tid] = v;
    __syncthreads();
    for (int off = 1; off < 256; off <<= 1) {
        int t = (tid >= off) ? s[tid - off] : 0;
        __syncthreads();
        s[tid] += t;
        __syncthreads();
    }
    if (i < n) rowstart[i] = s[tid] - v;   // exclusive within block
    if (tid == 255) bsum[blockIdx.x] = s[255];
}

// single-block exclusive scan of block sums (nb <= 256)
__global__ __launch_bounds__(256) void scan2_k(int* __restrict__ bsum, int nb) {
    __shared__ int s[256];
    int tid = threadIdx.x;
    int v = (tid < nb) ? bsum[tid] : 0;
    s[tid] = v;
    __syncthreads();
    for (int off = 1; off < 256; off <<= 1) {
        int t = (tid >= off) ? s[tid - off] : 0;
        __syncthreads();
        s[tid] += t;
        __syncthreads();
    }
    if (tid < nb) bsum[tid] = s[tid] - v;  // exclusive
}

__global__ void addoff_k(int* __restrict__ rowstart, const int* __restrict__ bsum, int n) {
    int i = blockIdx.x * blockDim.x + threadIdx.x;
    if (i < n) rowstart[i] += bsum[blockIdx.x];
}

__global__ void fill_csr_k(const int* __restrict__ src, const int* __restrict__ dst,
                           const int* __restrict__ rowstart, int* __restrict__ cursor,
                           int* __restrict__ csr, int nE) {
    int e = blockIdx.x * blockDim.x + threadIdx.x;
    if (e < nE) {
        int d = dst[e];
        int p = atomicAdd(&cursor[d], 1);
        csr[rowstart[d] + p] = src[e];
    }
}

// --- mean aggregation via CSR gather: one block per dst node ---------------
__global__ __launch_bounds__(128) void gather_mean_k(const float* __restrict__ feat,
                                                     const int* __restrict__ csr,
                                                     const int* __restrict__ rowstart,
                                                     const int* __restrict__ deg,
                                                     float* __restrict__ outm) {
    __shared__ int idxs[128];
    int node = blockIdx.x;
    int tid = threadIdx.x;
    int s0 = rowstart[node];
    int dc = deg[node];
    float acc = 0.0f;
    for (int base = 0; base < dc; base += 128) {
        int m = min(128, dc - base);
        __syncthreads();
        if (tid < m) idxs[tid] = csr[s0 + base + tid];
        __syncthreads();
        for (int j = 0; j < m; ++j)
            acc += feat[(size_t)idxs[j] * FDIM + tid];
    }
    float inv = (dc > 0) ? 1.0f / (float)dc : 0.0f;
    outm[(size_t)node * FDIM + tid] = acc * inv;
}

// --- fused SAGE layer GEMM: out = relu?( aggr @ wl + bias + root @ wr ) ----
// 256 threads: col = tid&127, half = tid>>7; 32 rows/block in 4 groups of 8.
// out may alias aggr: rows staged to LDS before the owning block writes back.
__global__ __launch_bounds__(256) void gemm_fused_k(
        const float* aggr, const float* __restrict__ root,
        const float* __restrict__ wl, const float* __restrict__ bias,
        const float* __restrict__ wr,
        float* out, int n, int do_relu) {
    __shared__ float wls[FDIM * FDIM];
    __shared__ float wrs[FDIM * FDIM];
    __shared__ float arow[8][FDIM];
    __shared__ float xrow[8][FDIM];

    int tid = threadIdx.x;
    int col = tid & 127, half = tid >> 7;
    for (int i = tid; i < FDIM * FDIM; i += 256) {
        wls[i] = wl[i];
        wrs[i] = wr[i];
    }
    float b = bias[col];
    int r0 = blockIdx.x * 32;

    for (int rg = 0; rg < 4; ++rg) {
        int rbase = r0 + rg * 8;
        __syncthreads();
        #pragma unroll
        for (int i = 0; i < 4; ++i) {
            int rr = rbase + i * 2 + half;           // slot s holds row rbase+s
            if (rr < n) {
                arow[i * 2 + half][col] = aggr[(size_t)rr * FDIM + col];
                xrow[i * 2 + half][col] = root[(size_t)rr * FDIM + col];
            }
        }
        __syncthreads();

        int rb = half * 4;
        float acc0 = b, acc1 = b, acc2 = b, acc3 = b;
        for (int k = 0; k < FDIM; ++k) {
            float wlv = wls[k * FDIM + col];
            float wrv = wrs[k * FDIM + col];
            acc0 += arow[rb + 0][k] * wlv + xrow[rb + 0][k] * wrv;
            acc1 += arow[rb + 1][k] * wlv + xrow[rb + 1][k] * wrv;
            acc2 += arow[rb + 2][k] * wlv + xrow[rb + 2][k] * wrv;
            acc3 += arow[rb + 3][k] * wlv + xrow[rb + 3][k] * wrv;
        }

        float acc[4] = {acc0, acc1, acc2, acc3};
        #pragma unroll
        for (int i = 0; i < 4; ++i) {
            int rr = rbase + rb + i;
            if (rr < n) {
                float v = acc[i];
                if (do_relu) v = fmaxf(v, 0.0f);
                out[(size_t)rr * FDIM + col] = v;
            }
        }
    }
}

// --- fused global mean pool + head (batch sorted -> binary search) ---------
__global__ __launch_bounds__(128) void pool_head_k(const float* __restrict__ h,
                                                   const int* __restrict__ batch,
                                                   const float* __restrict__ wf,
                                                   const float* __restrict__ bf,
                                                   float* __restrict__ out,
                                                   int nN, int nG) {
    __shared__ float row[FDIM];
    __shared__ int bounds[2];
    int g = blockIdx.x;
    int tid = threadIdx.x;
    if (tid == 0) {
        int lo = 0, hi = nN;
        while (lo < hi) { int mid = (lo + hi) >> 1; if (batch[mid] < g) lo = mid + 1; else hi = mid; }
        bounds[0] = lo;
        hi = nN;
        while (lo < hi) { int mid = (lo + hi) >> 1; if (batch[mid] < g + 1) lo = mid + 1; else hi = mid; }
        bounds[1] = lo;
    }
    __syncthreads();
    int s = bounds[0], e = bounds[1];
    float acc = 0.0f;
    for (int i = s; i < e; ++i) acc += h[(size_t)i * FDIM + tid];
    float inv = (e > s) ? 1.0f / (float)(e - s) : 1.0f;  // ref: / max(cnt,1)
    row[tid] = acc * inv;
    __syncthreads();

    float logit = -1e30f;
    if (tid < 16) {
        logit = bf[tid];
        for (int k = 0; k < FDIM; ++k) logit += row[k] * wf[k * 16 + tid];
    }
    float m = logit;
    for (int off = 8; off >= 1; off >>= 1) m = fmaxf(m, __shfl_xor(m, off, 64));
    float ev = (tid < 16) ? expf(logit - m) : 0.0f;
    float sum = ev;
    for (int off = 8; off >= 1; off >>= 1) sum += __shfl_xor(sum, off, 64);
    if (tid < 16) out[(size_t)g * 16 + tid] = logit - m - logf(sum);
}

extern "C" void kernel_launch(void* const* d_in, const int* in_sizes, int n_in,
                              void* d_out, int out_size, void* d_ws, size_t ws_size,
                              hipStream_t stream) {
    const float* x    = (const float*)d_in[0];
    const int*   ei   = (const int*)d_in[1];
    const int*   batch= (const int*)d_in[2];
    const float* w1l  = (const float*)d_in[3];
    const float* b1   = (const float*)d_in[4];
    const float* w1r  = (const float*)d_in[5];
    const float* w2l  = (const float*)d_in[6];
    const float* b2   = (const float*)d_in[7];
    const float* w2r  = (const float*)d_in[8];
    const float* wf   = (const float*)d_in[9];
    const float* bf   = (const float*)d_in[10];
    float* out = (float*)d_out;

    const int N = in_sizes[0] / FDIM;
    const int E = in_sizes[1] / 2;
    const int G = out_size / 16;
    const int* src = ei;
    const int* dst = ei + E;
    const int NB = (N + 255) / 256;   // <= 256 required by scan2_k

    // --- workspace layout (256B-aligned chunks) ---
    char* ws = (char*)d_ws;
    size_t off = 0;
    auto alloc = [&](size_t bytes) { void* p = ws + off; off = (off + bytes + 255) & ~(size_t)255; return p; };
    float* aggr     = (float*)alloc((size_t)N * FDIM * sizeof(float)); // also h2/out of layer2
    float* h1       = (float*)alloc((size_t)N * FDIM * sizeof(float));
    int*   deg      = (int*)alloc((size_t)N * sizeof(int));
    int*   rowstart = (int*)alloc((size_t)N * sizeof(int));
    int*   cursor   = (int*)alloc((size_t)N * sizeof(int));
    int*   bsum     = (int*)alloc(256 * sizeof(int));
    int*   csr      = (int*)alloc((size_t)E * sizeof(int));

    // --- CSR build ---
    hipMemsetAsync(deg, 0, (size_t)N * sizeof(int), stream);
    hipMemsetAsync(cursor, 0, (size_t)N * sizeof(int), stream);
    deg_count_k<<<(E + 255) / 256, 256, 0, stream>>>(dst, deg, E);
    scan1_k<<<NB, 256, 0, stream>>>(deg, rowstart, bsum, N);
    scan2_k<<<1, 256, 0, stream>>>(bsum, NB);
    addoff_k<<<NB, 256, 0, stream>>>(rowstart, bsum, N);
    fill_csr_k<<<(E + 255) / 256, 256, 0, stream>>>(src, dst, rowstart, cursor, csr, E);

    // --- layer 1 ---
    gather_mean_k<<<N, 128, 0, stream>>>(x, csr, rowstart, deg, aggr);
    gemm_fused_k<<<(N + 31) / 32, 256, 0, stream>>>(aggr, x, w1l, b1, w1r, h1, N, 1);

    // --- layer 2 ---
    gather_mean_k<<<N, 128, 0, stream>>>(h1, csr, rowstart, deg, aggr);
    gemm_fused_k<<<(N + 31) / 32, 256, 0, stream>>>(aggr, h1, w2l, b2, w2r, aggr, N, 1);

    // --- pool + head ---
    pool_head_k<<<G, 128, 0, stream>>>(aggr, batch, wf, bf, out, N, G);
}

// Round 3
// 337.773 us; speedup vs baseline: 11.4054x; 2.1470x over previous
//
#include <hip/hip_runtime.h>
#include <hip/hip_bf16.h>
#include <math.h>

// ---------------------------------------------------------------------------
// GraphSAGE inference, bf16 MFMA pipeline.
//   h1 = relu([aggr(x)|x] @ [w1l;w1r] + b1)      (MFMA, K=256)
//   h2 = relu([aggr(h1)|h1] @ [w2l;w2r] + b2)
//   out = log_softmax(mean_pool(h2) @ wf + bf)
// R1: atomics -> CSR+gather. R2: fp32 VALU GEMM -> bf16 MFMA, LDS-free,
//     weights pre-packed in fragment order; activations bf16 end-to-end.
// ---------------------------------------------------------------------------

#define FDIM 128

typedef __attribute__((ext_vector_type(8))) short bf16x8;
typedef __attribute__((ext_vector_type(4))) float f32x4;

__device__ inline unsigned short f2bf(float f) {
    union { float f; unsigned u; } v; v.f = f;
    unsigned r = v.u + 0x7fff + ((v.u >> 16) & 1);   // RNE
    return (unsigned short)(r >> 16);
}
__device__ inline float bf2f(unsigned short b) {
    union { unsigned u; float f; } v; v.u = ((unsigned)b) << 16;
    return v.f;
}

// --- CSR build -------------------------------------------------------------
__global__ void deg_count_k(const int* __restrict__ dst, int* __restrict__ deg, int nE) {
    int e = blockIdx.x * blockDim.x + threadIdx.x;
    if (e < nE) atomicAdd(&deg[dst[e]], 1);
}

__global__ __launch_bounds__(256) void scan1_k(const int* __restrict__ deg,
                                               int* __restrict__ rowstart,
                                               int* __restrict__ bsum, int n) {
    __shared__ int s[256];
    int tid = threadIdx.x;
    int i = blockIdx.x * 256 + tid;
    int v = (i < n) ? deg[i] : 0;
    s[tid] = v;
    __syncthreads();
    for (int off = 1; off < 256; off <<= 1) {
        int t = (tid >= off) ? s[tid - off] : 0;
        __syncthreads();
        s[tid] += t;
        __syncthreads();
    }
    if (i < n) rowstart[i] = s[tid] - v;
    if (tid == 255) bsum[blockIdx.x] = s[255];
}

__global__ __launch_bounds__(256) void scan2_k(int* __restrict__ bsum, int nb) {
    __shared__ int s[256];
    int tid = threadIdx.x;
    int v = (tid < nb) ? bsum[tid] : 0;
    s[tid] = v;
    __syncthreads();
    for (int off = 1; off < 256; off <<= 1) {
        int t = (tid >= off) ? s[tid - off] : 0;
        __syncthreads();
        s[tid] += t;
        __syncthreads();
    }
    if (tid < nb) bsum[tid] = s[tid] - v;
}

__global__ void addoff_k(int* __restrict__ rowstart, const int* __restrict__ bsum, int n) {
    int i = blockIdx.x * blockDim.x + threadIdx.x;
    if (i < n) rowstart[i] += bsum[blockIdx.x];
}

__global__ void fill_csr_k(const int* __restrict__ src, const int* __restrict__ dst,
                           const int* __restrict__ rowstart, int* __restrict__ cursor,
                           int* __restrict__ csr, int nE) {
    int e = blockIdx.x * blockDim.x + threadIdx.x;
    if (e < nE) {
        int d = dst[e];
        int p = atomicAdd(&cursor[d], 1);
        csr[rowstart[d] + p] = src[e];
    }
}

// --- f32 -> bf16 conversion (4 elems/thread) -------------------------------
__global__ void cvt_bf16_k(const float* __restrict__ in, unsigned short* __restrict__ outp,
                           int n4) {
    int i = blockIdx.x * blockDim.x + threadIdx.x;
    if (i >= n4) return;
    float4 v = ((const float4*)in)[i];
    ushort4 o;
    o.x = f2bf(v.x); o.y = f2bf(v.y); o.z = f2bf(v.z); o.w = f2bf(v.w);
    ((ushort4*)outp)[i] = o;
}

// --- pack [wl;wr] (256x128) into B-fragment order --------------------------
// wp[((nt*8+s)*64+lane)*8 + j] = W[s*32 + (lane>>4)*8 + j][nt*16 + (lane&15)]
// where W rows 0..127 = wl, 128..255 = wr.
__global__ __launch_bounds__(256) void pack_w_k(const float* __restrict__ wl,
                                                const float* __restrict__ wr,
                                                unsigned short* __restrict__ wp) {
    int t = blockIdx.x * 256 + threadIdx.x;      // 0..4095
    int lane = t & 63, s = (t >> 6) & 7, nt = t >> 9;
    int kbase = s * 32 + ((lane >> 4) * 8);
    int c = nt * 16 + (lane & 15);
    ushort4 lo, hi;
    unsigned short tmp[8];
    #pragma unroll
    for (int j = 0; j < 8; ++j) {
        int k = kbase + j;
        float w = (k < 128) ? wl[k * 128 + c] : wr[(k - 128) * 128 + c];
        tmp[j] = f2bf(w);
    }
    lo.x = tmp[0]; lo.y = tmp[1]; lo.z = tmp[2]; lo.w = tmp[3];
    hi.x = tmp[4]; hi.y = tmp[5]; hi.z = tmp[6]; hi.w = tmp[7];
    ((ushort4*)wp)[t * 2 + 0] = lo;
    ((ushort4*)wp)[t * 2 + 1] = hi;
}

// --- mean aggregation: one wave per node, bf16x2 per lane ------------------
__global__ __launch_bounds__(256) void gather_mean_k(
        const unsigned* __restrict__ feat2,       // [n][64] uints (bf16x2)
        const int* __restrict__ csr, const int* __restrict__ rowstart,
        const int* __restrict__ deg, unsigned* __restrict__ out2, int n) {
    int node = blockIdx.x * 4 + (threadIdx.x >> 6);
    int lane = threadIdx.x & 63;
    if (node >= n) return;
    int s0 = rowstart[node], dc = deg[node];
    float a0 = 0.0f, a1 = 0.0f;
    for (int j = 0; j < dc; ++j) {
        int idx = csr[s0 + j];                    // wave-uniform -> scalar load
        unsigned v = feat2[(size_t)idx * 64 + lane];
        a0 += bf2f((unsigned short)(v & 0xffff));
        a1 += bf2f((unsigned short)(v >> 16));
    }
    float inv = (dc > 0) ? 1.0f / (float)dc : 0.0f;
    unsigned o = ((unsigned)f2bf(a1 * inv) << 16) | (unsigned)f2bf(a0 * inv);
    out2[(size_t)node * 64 + lane] = o;
}

// --- fused SAGE GEMM: out = relu([A|R] @ Wpack + bias), bf16 MFMA ----------
// 256 thr = 4 waves; wave w owns rows blockIdx*64 + w*16 .. +15, all 128 cols.
// A fragments straight from global (row-major bf16); B from packed stream.
__global__ __launch_bounds__(256) void gemm_mfma_k(
        const unsigned short* __restrict__ A,     // aggr [n][128] bf16
        const unsigned short* __restrict__ R,     // root [n][128] bf16
        const unsigned short* __restrict__ wp,    // packed weights
        const float* __restrict__ bias,           // [128] f32
        unsigned short* __restrict__ outp,        // [n][128] bf16
        int n) {
    int tid = threadIdx.x;
    int wave = tid >> 6, lane = tid & 63;
    int rowTile = blockIdx.x * 64 + wave * 16;
    int lrow = lane & 15, lk = lane >> 4;

    int arow = rowTile + lrow;
    if (arow >= n) arow = n - 1;                  // clamp; stores are guarded

    bf16x8 a[8];
    const unsigned short* abase = A + (size_t)arow * FDIM + lk * 8;
    const unsigned short* rbase = R + (size_t)arow * FDIM + lk * 8;
    #pragma unroll
    for (int s = 0; s < 4; ++s) a[s] = *(const bf16x8*)(abase + s * 32);
    #pragma unroll
    for (int s = 0; s < 4; ++s) a[4 + s] = *(const bf16x8*)(rbase + s * 32);

    const bf16x8* bp = (const bf16x8*)wp;
    int ocol = lane & 15;
    int orow0 = rowTile + (lane >> 4) * 4;

    #pragma unroll
    for (int nt = 0; nt < 8; ++nt) {
        float bv = bias[nt * 16 + ocol];
        f32x4 acc = {bv, bv, bv, bv};
        #pragma unroll
        for (int s = 0; s < 8; ++s) {
            bf16x8 b = bp[(nt * 8 + s) * 64 + lane];
            acc = __builtin_amdgcn_mfma_f32_16x16x32_bf16(a[s], b, acc, 0, 0, 0);
        }
        #pragma unroll
        for (int r = 0; r < 4; ++r) {
            int orow = orow0 + r;
            if (orow < n) {
                float v = fmaxf(acc[r], 0.0f);
                outp[(size_t)orow * FDIM + nt * 16 + ocol] = f2bf(v);
            }
        }
    }
}

// --- fused global mean pool + head (batch sorted -> binary search) ---------
__global__ __launch_bounds__(128) void pool_head_k(const unsigned short* __restrict__ h,
                                                   const int* __restrict__ batch,
                                                   const float* __restrict__ wf,
                                                   const float* __restrict__ bf,
                                                   float* __restrict__ out,
                                                   int nN, int nG) {
    __shared__ float row[FDIM];
    __shared__ int bounds[2];
    int g = blockIdx.x;
    int tid = threadIdx.x;
    if (tid == 0) {
        int lo = 0, hi = nN;
        while (lo < hi) { int mid = (lo + hi) >> 1; if (batch[mid] < g) lo = mid + 1; else hi = mid; }
        bounds[0] = lo;
        hi = nN;
        while (lo < hi) { int mid = (lo + hi) >> 1; if (batch[mid] < g + 1) lo = mid + 1; else hi = mid; }
        bounds[1] = lo;
    }
    __syncthreads();
    int s = bounds[0], e = bounds[1];
    float acc = 0.0f;
    for (int i = s; i < e; ++i) acc += bf2f(h[(size_t)i * FDIM + tid]);
    float inv = (e > s) ? 1.0f / (float)(e - s) : 1.0f;
    row[tid] = acc * inv;
    __syncthreads();

    float logit = -1e30f;
    if (tid < 16) {
        logit = bf[tid];
        for (int k = 0; k < FDIM; ++k) logit += row[k] * wf[k * 16 + tid];
    }
    float m = logit;
    for (int off = 8; off >= 1; off >>= 1) m = fmaxf(m, __shfl_xor(m, off, 64));
    float ev = (tid < 16) ? expf(logit - m) : 0.0f;
    float sum = ev;
    for (int off = 8; off >= 1; off >>= 1) sum += __shfl_xor(sum, off, 64);
    if (tid < 16) out[(size_t)g * 16 + tid] = logit - m - logf(sum);
}

extern "C" void kernel_launch(void* const* d_in, const int* in_sizes, int n_in,
                              void* d_out, int out_size, void* d_ws, size_t ws_size,
                              hipStream_t stream) {
    const float* x    = (const float*)d_in[0];
    const int*   ei   = (const int*)d_in[1];
    const int*   batch= (const int*)d_in[2];
    const float* w1l  = (const float*)d_in[3];
    const float* b1   = (const float*)d_in[4];
    const float* w1r  = (const float*)d_in[5];
    const float* w2l  = (const float*)d_in[6];
    const float* b2   = (const float*)d_in[7];
    const float* w2r  = (const float*)d_in[8];
    const float* wf   = (const float*)d_in[9];
    const float* bf   = (const float*)d_in[10];
    float* out = (float*)d_out;

    const int N = in_sizes[0] / FDIM;
    const int E = in_sizes[1] / 2;
    const int G = out_size / 16;
    const int* src = ei;
    const int* dst = ei + E;
    const int NB = (N + 255) / 256;              // <= 256 for scan2_k

    // --- workspace layout ---
    char* ws = (char*)d_ws;
    size_t off = 0;
    auto alloc = [&](size_t bytes) { void* p = ws + off; off = (off + bytes + 255) & ~(size_t)255; return p; };
    unsigned short* xb   = (unsigned short*)alloc((size_t)N * FDIM * 2); // also h2
    unsigned short* aggr = (unsigned short*)alloc((size_t)N * FDIM * 2);
    unsigned short* h1   = (unsigned short*)alloc((size_t)N * FDIM * 2);
    unsigned short* wp1  = (unsigned short*)alloc(8 * 8 * 64 * 8 * 2);
    unsigned short* wp2  = (unsigned short*)alloc(8 * 8 * 64 * 8 * 2);
    int* deg      = (int*)alloc((size_t)N * sizeof(int));
    int* rowstart = (int*)alloc((size_t)N * sizeof(int));
    int* cursor   = (int*)alloc((size_t)N * sizeof(int));
    int* bsum     = (int*)alloc(256 * sizeof(int));
    int* csr      = (int*)alloc((size_t)E * sizeof(int));
    unsigned short* h2 = xb;                      // xb dead by the time h2 is written

    // --- CSR build ---
    hipMemsetAsync(deg, 0, (size_t)N * sizeof(int), stream);
    hipMemsetAsync(cursor, 0, (size_t)N * sizeof(int), stream);
    deg_count_k<<<(E + 255) / 256, 256, 0, stream>>>(dst, deg, E);
    scan1_k<<<NB, 256, 0, stream>>>(deg, rowstart, bsum, N);
    scan2_k<<<1, 256, 0, stream>>>(bsum, NB);
    addoff_k<<<NB, 256, 0, stream>>>(rowstart, bsum, N);
    fill_csr_k<<<(E + 255) / 256, 256, 0, stream>>>(src, dst, rowstart, cursor, csr, E);

    // --- prep: x -> bf16, pack weights ---
    cvt_bf16_k<<<(N * FDIM / 4 + 255) / 256, 256, 0, stream>>>(x, xb, N * FDIM / 4);
    pack_w_k<<<16, 256, 0, stream>>>(w1l, w1r, wp1);
    pack_w_k<<<16, 256, 0, stream>>>(w2l, w2r, wp2);

    // --- layer 1 ---
    gather_mean_k<<<(N + 3) / 4, 256, 0, stream>>>((const unsigned*)xb, csr, rowstart, deg,
                                                   (unsigned*)aggr, N);
    gemm_mfma_k<<<(N + 63) / 64, 256, 0, stream>>>(aggr, xb, wp1, b1, h1, N);

    // --- layer 2 ---
    gather_mean_k<<<(N + 3) / 4, 256, 0, stream>>>((const unsigned*)h1, csr, rowstart, deg,
                                                   (unsigned*)aggr, N);
    gemm_mfma_k<<<(N + 63) / 64, 256, 0, stream>>>(aggr, h1, wp2, b2, h2, N);

    // --- pool + head ---
    pool_head_k<<<G, 128, 0, stream>>>(h2, batch, wf, bf, out, N, G);
}

// Round 4
// 268.322 us; speedup vs baseline: 14.3576x; 1.2588x over previous
//
#include <hip/hip_runtime.h>
#include <hip/hip_bf16.h>
#include <math.h>

// ---------------------------------------------------------------------------
// GraphSAGE inference, bf16 MFMA pipeline.
//   h1 = relu([aggr(x)|x] @ [w1l;w1r] + b1)      (MFMA, K=256)
//   h2 = relu([aggr(h1)|h1] @ [w2l;w2r] + b2)
//   out = log_softmax(mean_pool(h2) @ wf + bf)
// R1: atomics -> CSR+gather. R2: bf16 MFMA GEMM, packed weights.
// R3: gather MLP - half-wave uint2 loads, 4 independent loads in flight.
// ---------------------------------------------------------------------------

#define FDIM 128

typedef __attribute__((ext_vector_type(8))) short bf16x8;
typedef __attribute__((ext_vector_type(4))) float f32x4;

__device__ inline unsigned short f2bf(float f) {
    union { float f; unsigned u; } v; v.f = f;
    unsigned r = v.u + 0x7fff + ((v.u >> 16) & 1);   // RNE
    return (unsigned short)(r >> 16);
}
__device__ inline float bf2f(unsigned short b) {
    union { unsigned u; float f; } v; v.u = ((unsigned)b) << 16;
    return v.f;
}

// --- CSR build -------------------------------------------------------------
__global__ void deg_count_k(const int* __restrict__ dst, int* __restrict__ deg, int nE) {
    int e = blockIdx.x * blockDim.x + threadIdx.x;
    if (e < nE) atomicAdd(&deg[dst[e]], 1);
}

__global__ __launch_bounds__(256) void scan1_k(const int* __restrict__ deg,
                                               int* __restrict__ rowstart,
                                               int* __restrict__ bsum, int n) {
    __shared__ int s[256];
    int tid = threadIdx.x;
    int i = blockIdx.x * 256 + tid;
    int v = (i < n) ? deg[i] : 0;
    s[tid] = v;
    __syncthreads();
    for (int off = 1; off < 256; off <<= 1) {
        int t = (tid >= off) ? s[tid - off] : 0;
        __syncthreads();
        s[tid] += t;
        __syncthreads();
    }
    if (i < n) rowstart[i] = s[tid] - v;
    if (tid == 255) bsum[blockIdx.x] = s[255];
}

__global__ __launch_bounds__(256) void scan2_k(int* __restrict__ bsum, int nb) {
    __shared__ int s[256];
    int tid = threadIdx.x;
    int v = (tid < nb) ? bsum[tid] : 0;
    s[tid] = v;
    __syncthreads();
    for (int off = 1; off < 256; off <<= 1) {
        int t = (tid >= off) ? s[tid - off] : 0;
        __syncthreads();
        s[tid] += t;
        __syncthreads();
    }
    if (tid < nb) bsum[tid] = s[tid] - v;
}

__global__ void addoff_k(int* __restrict__ rowstart, const int* __restrict__ bsum, int n) {
    int i = blockIdx.x * blockDim.x + threadIdx.x;
    if (i < n) rowstart[i] += bsum[blockIdx.x];
}

__global__ void fill_csr_k(const int* __restrict__ src, const int* __restrict__ dst,
                           const int* __restrict__ rowstart, int* __restrict__ cursor,
                           int* __restrict__ csr, int nE) {
    int e = blockIdx.x * blockDim.x + threadIdx.x;
    if (e < nE) {
        int d = dst[e];
        int p = atomicAdd(&cursor[d], 1);
        csr[rowstart[d] + p] = src[e];
    }
}

// --- f32 -> bf16 conversion (4 elems/thread) -------------------------------
__global__ void cvt_bf16_k(const float* __restrict__ in, unsigned short* __restrict__ outp,
                           int n4) {
    int i = blockIdx.x * blockDim.x + threadIdx.x;
    if (i >= n4) return;
    float4 v = ((const float4*)in)[i];
    ushort4 o;
    o.x = f2bf(v.x); o.y = f2bf(v.y); o.z = f2bf(v.z); o.w = f2bf(v.w);
    ((ushort4*)outp)[i] = o;
}

// --- pack [wl;wr] (256x128) into B-fragment order --------------------------
// wp[((nt*8+s)*64+lane)*8 + j] = W[s*32 + (lane>>4)*8 + j][nt*16 + (lane&15)]
// where W rows 0..127 = wl, 128..255 = wr.
__global__ __launch_bounds__(256) void pack_w_k(const float* __restrict__ wl,
                                                const float* __restrict__ wr,
                                                unsigned short* __restrict__ wp) {
    int t = blockIdx.x * 256 + threadIdx.x;      // 0..4095
    int lane = t & 63, s = (t >> 6) & 7, nt = t >> 9;
    int kbase = s * 32 + ((lane >> 4) * 8);
    int c = nt * 16 + (lane & 15);
    ushort4 lo, hi;
    unsigned short tmp[8];
    #pragma unroll
    for (int j = 0; j < 8; ++j) {
        int k = kbase + j;
        float w = (k < 128) ? wl[k * 128 + c] : wr[(k - 128) * 128 + c];
        tmp[j] = f2bf(w);
    }
    lo.x = tmp[0]; lo.y = tmp[1]; lo.z = tmp[2]; lo.w = tmp[3];
    hi.x = tmp[4]; hi.y = tmp[5]; hi.z = tmp[6]; hi.w = tmp[7];
    ((ushort4*)wp)[t * 2 + 0] = lo;
    ((ushort4*)wp)[t * 2 + 1] = hi;
}

// --- mean aggregation: one wave per node, half-wave edge streams -----------
// Lanes 0..31 handle edges base+{0,2,4,6}, lanes 32..63 edges base+{1,3,5,7}.
// Each lane loads uint2 (4 bf16) -> 4 independent 8B loads in flight/wave.
__global__ __launch_bounds__(256) void gather_mean_k(
        const uint2* __restrict__ feat,           // [n][32] uint2 (256B rows)
        const int* __restrict__ csr, const int* __restrict__ rowstart,
        const int* __restrict__ deg, uint2* __restrict__ outr, int n) {
    int node = blockIdx.x * 4 + (threadIdx.x >> 6);
    if (node >= n) return;
    int lane = threadIdx.x & 63;
    int h = lane >> 5;                            // half id: edge parity
    int hl = lane & 31;                           // lane within half
    int s0 = rowstart[node], dc = deg[node];

    float a0 = 0.f, a1 = 0.f, a2 = 0.f, a3 = 0.f;
    for (int base = 0; base < dc; base += 8) {
        int e0 = base + h, e1 = base + 2 + h, e2 = base + 4 + h, e3 = base + 6 + h;
        int i0 = (e0 < dc) ? csr[s0 + e0] : 0;
        int i1 = (e1 < dc) ? csr[s0 + e1] : 0;
        int i2 = (e2 < dc) ? csr[s0 + e2] : 0;
        int i3 = (e3 < dc) ? csr[s0 + e3] : 0;
        uint2 w0 = feat[(size_t)i0 * 32 + hl];
        uint2 w1 = feat[(size_t)i1 * 32 + hl];
        uint2 w2 = feat[(size_t)i2 * 32 + hl];
        uint2 w3 = feat[(size_t)i3 * 32 + hl];
        if (e0 >= dc) { w0.x = 0; w0.y = 0; }
        if (e1 >= dc) { w1.x = 0; w1.y = 0; }
        if (e2 >= dc) { w2.x = 0; w2.y = 0; }
        if (e3 >= dc) { w3.x = 0; w3.y = 0; }
        a0 += bf2f((unsigned short)(w0.x & 0xffff)) + bf2f((unsigned short)(w1.x & 0xffff))
            + bf2f((unsigned short)(w2.x & 0xffff)) + bf2f((unsigned short)(w3.x & 0xffff));
        a1 += bf2f((unsigned short)(w0.x >> 16)) + bf2f((unsigned short)(w1.x >> 16))
            + bf2f((unsigned short)(w2.x >> 16)) + bf2f((unsigned short)(w3.x >> 16));
        a2 += bf2f((unsigned short)(w0.y & 0xffff)) + bf2f((unsigned short)(w1.y & 0xffff))
            + bf2f((unsigned short)(w2.y & 0xffff)) + bf2f((unsigned short)(w3.y & 0xffff));
        a3 += bf2f((unsigned short)(w0.y >> 16)) + bf2f((unsigned short)(w1.y >> 16))
            + bf2f((unsigned short)(w2.y >> 16)) + bf2f((unsigned short)(w3.y >> 16));
    }
    // combine the two half-wave partial sums
    a0 += __shfl_xor(a0, 32, 64);
    a1 += __shfl_xor(a1, 32, 64);
    a2 += __shfl_xor(a2, 32, 64);
    a3 += __shfl_xor(a3, 32, 64);

    if (h == 0) {
        float inv = (dc > 0) ? 1.0f / (float)dc : 0.0f;
        uint2 o;
        o.x = ((unsigned)f2bf(a1 * inv) << 16) | (unsigned)f2bf(a0 * inv);
        o.y = ((unsigned)f2bf(a3 * inv) << 16) | (unsigned)f2bf(a2 * inv);
        outr[(size_t)node * 32 + hl] = o;
    }
}

// --- fused SAGE GEMM: out = relu([A|R] @ Wpack + bias), bf16 MFMA ----------
__global__ __launch_bounds__(256) void gemm_mfma_k(
        const unsigned short* __restrict__ A,     // aggr [n][128] bf16
        const unsigned short* __restrict__ R,     // root [n][128] bf16
        const unsigned short* __restrict__ wp,    // packed weights
        const float* __restrict__ bias,           // [128] f32
        unsigned short* __restrict__ outp,        // [n][128] bf16
        int n) {
    int tid = threadIdx.x;
    int wave = tid >> 6, lane = tid & 63;
    int rowTile = blockIdx.x * 64 + wave * 16;
    int lrow = lane & 15, lk = lane >> 4;

    int arow = rowTile + lrow;
    if (arow >= n) arow = n - 1;                  // clamp; stores are guarded

    bf16x8 a[8];
    const unsigned short* abase = A + (size_t)arow * FDIM + lk * 8;
    const unsigned short* rbase = R + (size_t)arow * FDIM + lk * 8;
    #pragma unroll
    for (int s = 0; s < 4; ++s) a[s] = *(const bf16x8*)(abase + s * 32);
    #pragma unroll
    for (int s = 0; s < 4; ++s) a[4 + s] = *(const bf16x8*)(rbase + s * 32);

    const bf16x8* bp = (const bf16x8*)wp;
    int ocol = lane & 15;
    int orow0 = rowTile + (lane >> 4) * 4;

    #pragma unroll
    for (int nt = 0; nt < 8; ++nt) {
        float bv = bias[nt * 16 + ocol];
        f32x4 acc = {bv, bv, bv, bv};
        #pragma unroll
        for (int s = 0; s < 8; ++s) {
            bf16x8 b = bp[(nt * 8 + s) * 64 + lane];
            acc = __builtin_amdgcn_mfma_f32_16x16x32_bf16(a[s], b, acc, 0, 0, 0);
        }
        #pragma unroll
        for (int r = 0; r < 4; ++r) {
            int orow = orow0 + r;
            if (orow < n) {
                float v = fmaxf(acc[r], 0.0f);
                outp[(size_t)orow * FDIM + nt * 16 + ocol] = f2bf(v);
            }
        }
    }
}

// --- fused global mean pool + head (batch sorted -> binary search) ---------
__global__ __launch_bounds__(128) void pool_head_k(const unsigned short* __restrict__ h,
                                                   const int* __restrict__ batch,
                                                   const float* __restrict__ wf,
                                                   const float* __restrict__ bf,
                                                   float* __restrict__ out,
                                                   int nN, int nG) {
    __shared__ float row[FDIM];
    __shared__ int bounds[2];
    int g = blockIdx.x;
    int tid = threadIdx.x;
    if (tid == 0) {
        int lo = 0, hi = nN;
        while (lo < hi) { int mid = (lo + hi) >> 1; if (batch[mid] < g) lo = mid + 1; else hi = mid; }
        bounds[0] = lo;
        hi = nN;
        while (lo < hi) { int mid = (lo + hi) >> 1; if (batch[mid] < g + 1) lo = mid + 1; else hi = mid; }
        bounds[1] = lo;
    }
    __syncthreads();
    int s = bounds[0], e = bounds[1];
    float acc = 0.0f;
    for (int i = s; i < e; ++i) acc += bf2f(h[(size_t)i * FDIM + tid]);
    float inv = (e > s) ? 1.0f / (float)(e - s) : 1.0f;
    row[tid] = acc * inv;
    __syncthreads();

    float logit = -1e30f;
    if (tid < 16) {
        logit = bf[tid];
        for (int k = 0; k < FDIM; ++k) logit += row[k] * wf[k * 16 + tid];
    }
    float m = logit;
    for (int off = 8; off >= 1; off >>= 1) m = fmaxf(m, __shfl_xor(m, off, 64));
    float ev = (tid < 16) ? expf(logit - m) : 0.0f;
    float sum = ev;
    for (int off = 8; off >= 1; off >>= 1) sum += __shfl_xor(sum, off, 64);
    if (tid < 16) out[(size_t)g * 16 + tid] = logit - m - logf(sum);
}

extern "C" void kernel_launch(void* const* d_in, const int* in_sizes, int n_in,
                              void* d_out, int out_size, void* d_ws, size_t ws_size,
                              hipStream_t stream) {
    const float* x    = (const float*)d_in[0];
    const int*   ei   = (const int*)d_in[1];
    const int*   batch= (const int*)d_in[2];
    const float* w1l  = (const float*)d_in[3];
    const float* b1   = (const float*)d_in[4];
    const float* w1r  = (const float*)d_in[5];
    const float* w2l  = (const float*)d_in[6];
    const float* b2   = (const float*)d_in[7];
    const float* w2r  = (const float*)d_in[8];
    const float* wf   = (const float*)d_in[9];
    const float* bf   = (const float*)d_in[10];
    float* out = (float*)d_out;

    const int N = in_sizes[0] / FDIM;
    const int E = in_sizes[1] / 2;
    const int G = out_size / 16;
    const int* src = ei;
    const int* dst = ei + E;
    const int NB = (N + 255) / 256;              // <= 256 for scan2_k

    // --- workspace layout ---
    char* ws = (char*)d_ws;
    size_t off = 0;
    auto alloc = [&](size_t bytes) { void* p = ws + off; off = (off + bytes + 255) & ~(size_t)255; return p; };
    unsigned short* xb   = (unsigned short*)alloc((size_t)N * FDIM * 2); // also h2
    unsigned short* aggr = (unsigned short*)alloc((size_t)N * FDIM * 2);
    unsigned short* h1   = (unsigned short*)alloc((size_t)N * FDIM * 2);
    unsigned short* wp1  = (unsigned short*)alloc(8 * 8 * 64 * 8 * 2);
    unsigned short* wp2  = (unsigned short*)alloc(8 * 8 * 64 * 8 * 2);
    int* deg      = (int*)alloc((size_t)N * sizeof(int));
    int* rowstart = (int*)alloc((size_t)N * sizeof(int));
    int* cursor   = (int*)alloc((size_t)N * sizeof(int));
    int* bsum     = (int*)alloc(256 * sizeof(int));
    int* csr      = (int*)alloc((size_t)E * sizeof(int));
    unsigned short* h2 = xb;                      // xb dead by the time h2 is written

    // --- CSR build ---
    hipMemsetAsync(deg, 0, (size_t)N * sizeof(int), stream);
    hipMemsetAsync(cursor, 0, (size_t)N * sizeof(int), stream);
    deg_count_k<<<(E + 255) / 256, 256, 0, stream>>>(dst, deg, E);
    scan1_k<<<NB, 256, 0, stream>>>(deg, rowstart, bsum, N);
    scan2_k<<<1, 256, 0, stream>>>(bsum, NB);
    addoff_k<<<NB, 256, 0, stream>>>(rowstart, bsum, N);
    fill_csr_k<<<(E + 255) / 256, 256, 0, stream>>>(src, dst, rowstart, cursor, csr, E);

    // --- prep: x -> bf16, pack weights ---
    cvt_bf16_k<<<(N * FDIM / 4 + 255) / 256, 256, 0, stream>>>(x, xb, N * FDIM / 4);
    pack_w_k<<<16, 256, 0, stream>>>(w1l, w1r, wp1);
    pack_w_k<<<16, 256, 0, stream>>>(w2l, w2r, wp2);

    // --- layer 1 ---
    gather_mean_k<<<(N + 3) / 4, 256, 0, stream>>>((const uint2*)xb, csr, rowstart, deg,
                                                   (uint2*)aggr, N);
    gemm_mfma_k<<<(N + 63) / 64, 256, 0, stream>>>(aggr, xb, wp1, b1, h1, N);

    // --- layer 2 ---
    gather_mean_k<<<(N + 3) / 4, 256, 0, stream>>>((const uint2*)h1, csr, rowstart, deg,
                                                   (uint2*)aggr, N);
    gemm_mfma_k<<<(N + 63) / 64, 256, 0, stream>>>(aggr, h1, wp2, b2, h2, N);

    // --- pool + head ---
    pool_head_k<<<G, 128, 0, stream>>>(h2, batch, wf, bf, out, N, G);
}

// Round 5
// 233.095 us; speedup vs baseline: 16.5274x; 1.1511x over previous
//
#include <hip/hip_runtime.h>
#include <hip/hip_bf16.h>
#include <math.h>

// ---------------------------------------------------------------------------
// GraphSAGE inference, bf16 MFMA pipeline.
//   h1 = relu([aggr(x)|x] @ [w1l;w1r] + b1)      (MFMA, K=256)
//   h2 = relu([aggr(h1)|h1] @ [w2l;w2r] + b2)
//   out = log_softmax(mean_pool(h2) @ wf + bf)
// R1: atomics -> CSR+gather. R2: bf16 MFMA GEMM, packed weights.
// R3: gather MLP - half-wave uint2 loads. R4: atomic-free localized CSR fill
//     (rank pass + class-partitioned scatter), gather unroll x8.
// ---------------------------------------------------------------------------

#define FDIM 128

typedef __attribute__((ext_vector_type(8))) short bf16x8;
typedef __attribute__((ext_vector_type(4))) float f32x4;

__device__ inline unsigned short f2bf(float f) {
    union { float f; unsigned u; } v; v.f = f;
    unsigned r = v.u + 0x7fff + ((v.u >> 16) & 1);   // RNE
    return (unsigned short)(r >> 16);
}
__device__ inline float bf2f(unsigned short b) {
    union { unsigned u; float f; } v; v.u = ((unsigned)b) << 16;
    return v.f;
}

// --- degree + per-edge rank (one atomic pass; rank written sequentially) ---
__global__ void deg_rank_k(const int* __restrict__ dst, int* __restrict__ deg,
                           int* __restrict__ rank, int nE) {
    int e = blockIdx.x * blockDim.x + threadIdx.x;
    if (e < nE) rank[e] = atomicAdd(&deg[dst[e]], 1);
}

__global__ __launch_bounds__(256) void scan1_k(const int* __restrict__ deg,
                                               int* __restrict__ rowstart,
                                               int* __restrict__ bsum, int n) {
    __shared__ int s[256];
    int tid = threadIdx.x;
    int i = blockIdx.x * 256 + tid;
    int v = (i < n) ? deg[i] : 0;
    s[tid] = v;
    __syncthreads();
    for (int off = 1; off < 256; off <<= 1) {
        int t = (tid >= off) ? s[tid - off] : 0;
        __syncthreads();
        s[tid] += t;
        __syncthreads();
    }
    if (i < n) rowstart[i] = s[tid] - v;
    if (tid == 255) bsum[blockIdx.x] = s[255];
}

__global__ __launch_bounds__(256) void scan2_k(int* __restrict__ bsum, int nb) {
    __shared__ int s[256];
    int tid = threadIdx.x;
    int v = (tid < nb) ? bsum[tid] : 0;
    s[tid] = v;
    __syncthreads();
    for (int off = 1; off < 256; off <<= 1) {
        int t = (tid >= off) ? s[tid - off] : 0;
        __syncthreads();
        s[tid] += t;
        __syncthreads();
    }
    if (tid < nb) bsum[tid] = s[tid] - v;
}

__global__ void addoff_k(int* __restrict__ rowstart, const int* __restrict__ bsum, int n) {
    int i = blockIdx.x * blockDim.x + threadIdx.x;
    if (i < n) rowstart[i] += bsum[blockIdx.x];
}

// --- atomic-free CSR fill, class-partitioned by node range -----------------
// Block class (blockIdx&7) handles only dst in its node range -> each csr
// window (~N/8 rows) is written by one block class (≈ one XCD under the
// round-robin dispatch heuristic), so lines coalesce in L2. Correct for any
// block->XCD mapping: classes partition edges exactly once.
__global__ __launch_bounds__(256) void fill_swz_k(
        const int* __restrict__ src, const int* __restrict__ dst,
        const int* __restrict__ rowstart, const int* __restrict__ rank,
        int* __restrict__ csr, int nE, int rngSize) {
    int cls = blockIdx.x & 7;
    int lo = cls * rngSize, hi = lo + rngSize;
    int nb = gridDim.x >> 3;
    int bi = blockIdx.x >> 3;
    for (int e = bi * 256 + threadIdx.x; e < nE; e += nb * 256) {
        int d = dst[e];
        if (d >= lo && d < hi)
            csr[rowstart[d] + rank[e]] = src[e];
    }
}

// --- f32 -> bf16 conversion (4 elems/thread) -------------------------------
__global__ void cvt_bf16_k(const float* __restrict__ in, unsigned short* __restrict__ outp,
                           int n4) {
    int i = blockIdx.x * blockDim.x + threadIdx.x;
    if (i >= n4) return;
    float4 v = ((const float4*)in)[i];
    ushort4 o;
    o.x = f2bf(v.x); o.y = f2bf(v.y); o.z = f2bf(v.z); o.w = f2bf(v.w);
    ((ushort4*)outp)[i] = o;
}

// --- pack [wl;wr] (256x128) into B-fragment order --------------------------
// wp[((nt*8+s)*64+lane)*8 + j] = W[s*32 + (lane>>4)*8 + j][nt*16 + (lane&15)]
__global__ __launch_bounds__(256) void pack_w_k(const float* __restrict__ wl,
                                                const float* __restrict__ wr,
                                                unsigned short* __restrict__ wp) {
    int t = blockIdx.x * 256 + threadIdx.x;      // 0..4095
    int lane = t & 63, s = (t >> 6) & 7, nt = t >> 9;
    int kbase = s * 32 + ((lane >> 4) * 8);
    int c = nt * 16 + (lane & 15);
    ushort4 lo, hi;
    unsigned short tmp[8];
    #pragma unroll
    for (int j = 0; j < 8; ++j) {
        int k = kbase + j;
        float w = (k < 128) ? wl[k * 128 + c] : wr[(k - 128) * 128 + c];
        tmp[j] = f2bf(w);
    }
    lo.x = tmp[0]; lo.y = tmp[1]; lo.z = tmp[2]; lo.w = tmp[3];
    hi.x = tmp[4]; hi.y = tmp[5]; hi.z = tmp[6]; hi.w = tmp[7];
    ((ushort4*)wp)[t * 2 + 0] = lo;
    ((ushort4*)wp)[t * 2 + 1] = hi;
}

// --- mean aggregation: one wave per node, half-wave edge streams -----------
// Lanes 0..31 handle even edge slots, 32..63 odd; 8 uint2 loads in flight.
__global__ __launch_bounds__(256) void gather_mean_k(
        const uint2* __restrict__ feat,           // [n][32] uint2 (256B rows)
        const int* __restrict__ csr, const int* __restrict__ rowstart,
        const int* __restrict__ deg, uint2* __restrict__ outr, int n) {
    int node = blockIdx.x * 4 + (threadIdx.x >> 6);
    if (node >= n) return;
    int lane = threadIdx.x & 63;
    int h = lane >> 5;                            // half id: edge parity
    int hl = lane & 31;                           // lane within half
    int s0 = rowstart[node], dc = deg[node];

    float a0 = 0.f, a1 = 0.f, a2 = 0.f, a3 = 0.f;
    for (int base = 0; base < dc; base += 16) {
        uint2 w[8];
        #pragma unroll
        for (int k = 0; k < 8; ++k) {
            int e = base + 2 * k + h;
            int idx = (e < dc) ? csr[s0 + e] : 0;
            w[k] = feat[(size_t)idx * 32 + hl];
        }
        #pragma unroll
        for (int k = 0; k < 8; ++k) {
            int e = base + 2 * k + h;
            if (e >= dc) { w[k].x = 0; w[k].y = 0; }
            a0 += bf2f((unsigned short)(w[k].x & 0xffff));
            a1 += bf2f((unsigned short)(w[k].x >> 16));
            a2 += bf2f((unsigned short)(w[k].y & 0xffff));
            a3 += bf2f((unsigned short)(w[k].y >> 16));
        }
    }
    a0 += __shfl_xor(a0, 32, 64);
    a1 += __shfl_xor(a1, 32, 64);
    a2 += __shfl_xor(a2, 32, 64);
    a3 += __shfl_xor(a3, 32, 64);

    if (h == 0) {
        float inv = (dc > 0) ? 1.0f / (float)dc : 0.0f;
        uint2 o;
        o.x = ((unsigned)f2bf(a1 * inv) << 16) | (unsigned)f2bf(a0 * inv);
        o.y = ((unsigned)f2bf(a3 * inv) << 16) | (unsigned)f2bf(a2 * inv);
        outr[(size_t)node * 32 + hl] = o;
    }
}

// --- fused SAGE GEMM: out = relu([A|R] @ Wpack + bias), bf16 MFMA ----------
__global__ __launch_bounds__(256) void gemm_mfma_k(
        const unsigned short* __restrict__ A,     // aggr [n][128] bf16
        const unsigned short* __restrict__ R,     // root [n][128] bf16
        const unsigned short* __restrict__ wp,    // packed weights
        const float* __restrict__ bias,           // [128] f32
        unsigned short* __restrict__ outp,        // [n][128] bf16
        int n) {
    int tid = threadIdx.x;
    int wave = tid >> 6, lane = tid & 63;
    int rowTile = blockIdx.x * 64 + wave * 16;
    int lrow = lane & 15, lk = lane >> 4;

    int arow = rowTile + lrow;
    if (arow >= n) arow = n - 1;                  // clamp; stores are guarded

    bf16x8 a[8];
    const unsigned short* abase = A + (size_t)arow * FDIM + lk * 8;
    const unsigned short* rbase = R + (size_t)arow * FDIM + lk * 8;
    #pragma unroll
    for (int s = 0; s < 4; ++s) a[s] = *(const bf16x8*)(abase + s * 32);
    #pragma unroll
    for (int s = 0; s < 4; ++s) a[4 + s] = *(const bf16x8*)(rbase + s * 32);

    const bf16x8* bp = (const bf16x8*)wp;
    int ocol = lane & 15;
    int orow0 = rowTile + (lane >> 4) * 4;

    #pragma unroll
    for (int nt = 0; nt < 8; ++nt) {
        float bv = bias[nt * 16 + ocol];
        f32x4 acc = {bv, bv, bv, bv};
        #pragma unroll
        for (int s = 0; s < 8; ++s) {
            bf16x8 b = bp[(nt * 8 + s) * 64 + lane];
            acc = __builtin_amdgcn_mfma_f32_16x16x32_bf16(a[s], b, acc, 0, 0, 0);
        }
        #pragma unroll
        for (int r = 0; r < 4; ++r) {
            int orow = orow0 + r;
            if (orow < n) {
                float v = fmaxf(acc[r], 0.0f);
                outp[(size_t)orow * FDIM + nt * 16 + ocol] = f2bf(v);
            }
        }
    }
}

// --- fused global mean pool + head (batch sorted -> binary search) ---------
__global__ __launch_bounds__(128) void pool_head_k(const unsigned short* __restrict__ h,
                                                   const int* __restrict__ batch,
                                                   const float* __restrict__ wf,
                                                   const float* __restrict__ bf,
                                                   float* __restrict__ out,
                                                   int nN, int nG) {
    __shared__ float row[FDIM];
    __shared__ int bounds[2];
    int g = blockIdx.x;
    int tid = threadIdx.x;
    if (tid == 0) {
        int lo = 0, hi = nN;
        while (lo < hi) { int mid = (lo + hi) >> 1; if (batch[mid] < g) lo = mid + 1; else hi = mid; }
        bounds[0] = lo;
        hi = nN;
        while (lo < hi) { int mid = (lo + hi) >> 1; if (batch[mid] < g + 1) lo = mid + 1; else hi = mid; }
        bounds[1] = lo;
    }
    __syncthreads();
    int s = bounds[0], e = bounds[1];
    float acc = 0.0f;
    for (int i = s; i < e; ++i) acc += bf2f(h[(size_t)i * FDIM + tid]);
    float inv = (e > s) ? 1.0f / (float)(e - s) : 1.0f;
    row[tid] = acc * inv;
    __syncthreads();

    float logit = -1e30f;
    if (tid < 16) {
        logit = bf[tid];
        for (int k = 0; k < FDIM; ++k) logit += row[k] * wf[k * 16 + tid];
    }
    float m = logit;
    for (int off = 8; off >= 1; off >>= 1) m = fmaxf(m, __shfl_xor(m, off, 64));
    float ev = (tid < 16) ? expf(logit - m) : 0.0f;
    float sum = ev;
    for (int off = 8; off >= 1; off >>= 1) sum += __shfl_xor(sum, off, 64);
    if (tid < 16) out[(size_t)g * 16 + tid] = logit - m - logf(sum);
}

extern "C" void kernel_launch(void* const* d_in, const int* in_sizes, int n_in,
                              void* d_out, int out_size, void* d_ws, size_t ws_size,
                              hipStream_t stream) {
    const float* x    = (const float*)d_in[0];
    const int*   ei   = (const int*)d_in[1];
    const int*   batch= (const int*)d_in[2];
    const float* w1l  = (const float*)d_in[3];
    const float* b1   = (const float*)d_in[4];
    const float* w1r  = (const float*)d_in[5];
    const float* w2l  = (const float*)d_in[6];
    const float* b2   = (const float*)d_in[7];
    const float* w2r  = (const float*)d_in[8];
    const float* wf   = (const float*)d_in[9];
    const float* bf   = (const float*)d_in[10];
    float* out = (float*)d_out;

    const int N = in_sizes[0] / FDIM;
    const int E = in_sizes[1] / 2;
    const int G = out_size / 16;
    const int* src = ei;
    const int* dst = ei + E;
    const int NB = (N + 255) / 256;              // <= 256 for scan2_k

    // --- workspace layout ---
    char* ws = (char*)d_ws;
    size_t off = 0;
    auto alloc = [&](size_t bytes) { void* p = ws + off; off = (off + bytes + 255) & ~(size_t)255; return p; };
    unsigned short* xb   = (unsigned short*)alloc((size_t)N * FDIM * 2); // also h2
    unsigned short* aggr = (unsigned short*)alloc((size_t)N * FDIM * 2);
    unsigned short* h1   = (unsigned short*)alloc((size_t)N * FDIM * 2);
    unsigned short* wp1  = (unsigned short*)alloc(8 * 8 * 64 * 8 * 2);
    unsigned short* wp2  = (unsigned short*)alloc(8 * 8 * 64 * 8 * 2);
    int* deg      = (int*)alloc((size_t)N * sizeof(int));
    int* rowstart = (int*)alloc((size_t)N * sizeof(int));
    int* bsum     = (int*)alloc(256 * sizeof(int));
    int* csr      = (int*)alloc((size_t)E * sizeof(int));
    int* rank     = (int*)alloc((size_t)E * sizeof(int));
    unsigned short* h2 = xb;                      // xb dead by the time h2 is written

    // --- CSR build (atomic-free localized fill) ---
    hipMemsetAsync(deg, 0, (size_t)N * sizeof(int), stream);
    deg_rank_k<<<(E + 255) / 256, 256, 0, stream>>>(dst, deg, rank, E);
    scan1_k<<<NB, 256, 0, stream>>>(deg, rowstart, bsum, N);
    scan2_k<<<1, 256, 0, stream>>>(bsum, NB);
    addoff_k<<<NB, 256, 0, stream>>>(rowstart, bsum, N);
    {
        int rngSize = (N + 7) / 8;
        fill_swz_k<<<2048, 256, 0, stream>>>(src, dst, rowstart, rank, csr, E, rngSize);
    }

    // --- prep: x -> bf16, pack weights ---
    cvt_bf16_k<<<(N * FDIM / 4 + 255) / 256, 256, 0, stream>>>(x, xb, N * FDIM / 4);
    pack_w_k<<<16, 256, 0, stream>>>(w1l, w1r, wp1);
    pack_w_k<<<16, 256, 0, stream>>>(w2l, w2r, wp2);

    // --- layer 1 ---
    gather_mean_k<<<(N + 3) / 4, 256, 0, stream>>>((const uint2*)xb, csr, rowstart, deg,
                                                   (uint2*)aggr, N);
    gemm_mfma_k<<<(N + 63) / 64, 256, 0, stream>>>(aggr, xb, wp1, b1, h1, N);

    // --- layer 2 ---
    gather_mean_k<<<(N + 3) / 4, 256, 0, stream>>>((const uint2*)h1, csr, rowstart, deg,
                                                   (uint2*)aggr, N);
    gemm_mfma_k<<<(N + 63) / 64, 256, 0, stream>>>(aggr, h1, wp2, b2, h2, N);

    // --- pool + head ---
    pool_head_k<<<G, 128, 0, stream>>>(h2, batch, wf, bf, out, N, G);
}

// Round 6
// 212.993 us; speedup vs baseline: 18.0873x; 1.0944x over previous
//
#include <hip/hip_runtime.h>
#include <hip/hip_bf16.h>
#include <math.h>

// ---------------------------------------------------------------------------
// GraphSAGE inference, bf16 MFMA pipeline.
//   h1 = relu([aggr(x)|x] @ [w1l;w1r] + b1)      (MFMA, K=256)
//   h2 = relu([aggr(h1)|h1] @ [w2l;w2r] + b2)
//   out = log_softmax(mean_pool(h2) @ wf + bf)
// R1: atomics -> CSR+gather. R2: bf16 MFMA GEMM, packed weights.
// R3: gather MLP - half-wave uint2 loads. R4: atomic-free localized CSR fill.
// R5: segmented parallel pool (batch sorted) - pool_head was 7.8%-occupancy
//     latency-bound at 43us; now 782 blocks + f32 atomic segment combine.
// ---------------------------------------------------------------------------

#define FDIM 128

typedef __attribute__((ext_vector_type(8))) short bf16x8;
typedef __attribute__((ext_vector_type(4))) float f32x4;

__device__ inline unsigned short f2bf(float f) {
    union { float f; unsigned u; } v; v.f = f;
    unsigned r = v.u + 0x7fff + ((v.u >> 16) & 1);   // RNE
    return (unsigned short)(r >> 16);
}
__device__ inline float bf2f(unsigned short b) {
    union { unsigned u; float f; } v; v.u = ((unsigned)b) << 16;
    return v.f;
}

// --- degree + per-edge rank (one atomic pass; rank written sequentially) ---
__global__ void deg_rank_k(const int* __restrict__ dst, int* __restrict__ deg,
                           int* __restrict__ rank, int nE) {
    int e = blockIdx.x * blockDim.x + threadIdx.x;
    if (e < nE) rank[e] = atomicAdd(&deg[dst[e]], 1);
}

__global__ __launch_bounds__(256) void scan1_k(const int* __restrict__ deg,
                                               int* __restrict__ rowstart,
                                               int* __restrict__ bsum, int n) {
    __shared__ int s[256];
    int tid = threadIdx.x;
    int i = blockIdx.x * 256 + tid;
    int v = (i < n) ? deg[i] : 0;
    s[tid] = v;
    __syncthreads();
    for (int off = 1; off < 256; off <<= 1) {
        int t = (tid >= off) ? s[tid - off] : 0;
        __syncthreads();
        s[tid] += t;
        __syncthreads();
    }
    if (i < n) rowstart[i] = s[tid] - v;
    if (tid == 255) bsum[blockIdx.x] = s[255];
}

__global__ __launch_bounds__(256) void scan2_k(int* __restrict__ bsum, int nb) {
    __shared__ int s[256];
    int tid = threadIdx.x;
    int v = (tid < nb) ? bsum[tid] : 0;
    s[tid] = v;
    __syncthreads();
    for (int off = 1; off < 256; off <<= 1) {
        int t = (tid >= off) ? s[tid - off] : 0;
        __syncthreads();
        s[tid] += t;
        __syncthreads();
    }
    if (tid < nb) bsum[tid] = s[tid] - v;
}

__global__ void addoff_k(int* __restrict__ rowstart, const int* __restrict__ bsum, int n) {
    int i = blockIdx.x * blockDim.x + threadIdx.x;
    if (i < n) rowstart[i] += bsum[blockIdx.x];
}

// --- atomic-free CSR fill, class-partitioned by node range -----------------
__global__ __launch_bounds__(256) void fill_swz_k(
        const int* __restrict__ src, const int* __restrict__ dst,
        const int* __restrict__ rowstart, const int* __restrict__ rank,
        int* __restrict__ csr, int nE, int rngSize) {
    int cls = blockIdx.x & 7;
    int lo = cls * rngSize, hi = lo + rngSize;
    int nb = gridDim.x >> 3;
    int bi = blockIdx.x >> 3;
    for (int e = bi * 256 + threadIdx.x; e < nE; e += nb * 256) {
        int d = dst[e];
        if (d >= lo && d < hi)
            csr[rowstart[d] + rank[e]] = src[e];
    }
}

// --- f32 -> bf16 conversion (4 elems/thread) -------------------------------
__global__ void cvt_bf16_k(const float* __restrict__ in, unsigned short* __restrict__ outp,
                           int n4) {
    int i = blockIdx.x * blockDim.x + threadIdx.x;
    if (i >= n4) return;
    float4 v = ((const float4*)in)[i];
    ushort4 o;
    o.x = f2bf(v.x); o.y = f2bf(v.y); o.z = f2bf(v.z); o.w = f2bf(v.w);
    ((ushort4*)outp)[i] = o;
}

// --- pack [wl;wr] (256x128) into B-fragment order --------------------------
__global__ __launch_bounds__(256) void pack_w_k(const float* __restrict__ wl,
                                                const float* __restrict__ wr,
                                                unsigned short* __restrict__ wp) {
    int t = blockIdx.x * 256 + threadIdx.x;      // 0..4095
    int lane = t & 63, s = (t >> 6) & 7, nt = t >> 9;
    int kbase = s * 32 + ((lane >> 4) * 8);
    int c = nt * 16 + (lane & 15);
    ushort4 lo, hi;
    unsigned short tmp[8];
    #pragma unroll
    for (int j = 0; j < 8; ++j) {
        int k = kbase + j;
        float w = (k < 128) ? wl[k * 128 + c] : wr[(k - 128) * 128 + c];
        tmp[j] = f2bf(w);
    }
    lo.x = tmp[0]; lo.y = tmp[1]; lo.z = tmp[2]; lo.w = tmp[3];
    hi.x = tmp[4]; hi.y = tmp[5]; hi.z = tmp[6]; hi.w = tmp[7];
    ((ushort4*)wp)[t * 2 + 0] = lo;
    ((ushort4*)wp)[t * 2 + 1] = hi;
}

// --- mean aggregation: one wave per node, half-wave edge streams -----------
__global__ __launch_bounds__(256) void gather_mean_k(
        const uint2* __restrict__ feat,           // [n][32] uint2 (256B rows)
        const int* __restrict__ csr, const int* __restrict__ rowstart,
        const int* __restrict__ deg, uint2* __restrict__ outr, int n) {
    int node = blockIdx.x * 4 + (threadIdx.x >> 6);
    if (node >= n) return;
    int lane = threadIdx.x & 63;
    int h = lane >> 5;                            // half id: edge parity
    int hl = lane & 31;                           // lane within half
    int s0 = rowstart[node], dc = deg[node];

    float a0 = 0.f, a1 = 0.f, a2 = 0.f, a3 = 0.f;
    for (int base = 0; base < dc; base += 16) {
        uint2 w[8];
        #pragma unroll
        for (int k = 0; k < 8; ++k) {
            int e = base + 2 * k + h;
            int idx = (e < dc) ? csr[s0 + e] : 0;
            w[k] = feat[(size_t)idx * 32 + hl];
        }
        #pragma unroll
        for (int k = 0; k < 8; ++k) {
            int e = base + 2 * k + h;
            if (e >= dc) { w[k].x = 0; w[k].y = 0; }
            a0 += bf2f((unsigned short)(w[k].x & 0xffff));
            a1 += bf2f((unsigned short)(w[k].x >> 16));
            a2 += bf2f((unsigned short)(w[k].y & 0xffff));
            a3 += bf2f((unsigned short)(w[k].y >> 16));
        }
    }
    a0 += __shfl_xor(a0, 32, 64);
    a1 += __shfl_xor(a1, 32, 64);
    a2 += __shfl_xor(a2, 32, 64);
    a3 += __shfl_xor(a3, 32, 64);

    if (h == 0) {
        float inv = (dc > 0) ? 1.0f / (float)dc : 0.0f;
        uint2 o;
        o.x = ((unsigned)f2bf(a1 * inv) << 16) | (unsigned)f2bf(a0 * inv);
        o.y = ((unsigned)f2bf(a3 * inv) << 16) | (unsigned)f2bf(a2 * inv);
        outr[(size_t)node * 32 + hl] = o;
    }
}

// --- fused SAGE GEMM: out = relu([A|R] @ Wpack + bias), bf16 MFMA ----------
__global__ __launch_bounds__(256) void gemm_mfma_k(
        const unsigned short* __restrict__ A,     // aggr [n][128] bf16
        const unsigned short* __restrict__ R,     // root [n][128] bf16
        const unsigned short* __restrict__ wp,    // packed weights
        const float* __restrict__ bias,           // [128] f32
        unsigned short* __restrict__ outp,        // [n][128] bf16
        int n) {
    int tid = threadIdx.x;
    int wave = tid >> 6, lane = tid & 63;
    int rowTile = blockIdx.x * 64 + wave * 16;
    int lrow = lane & 15, lk = lane >> 4;

    int arow = rowTile + lrow;
    if (arow >= n) arow = n - 1;                  // clamp; stores are guarded

    bf16x8 a[8];
    const unsigned short* abase = A + (size_t)arow * FDIM + lk * 8;
    const unsigned short* rbase = R + (size_t)arow * FDIM + lk * 8;
    #pragma unroll
    for (int s = 0; s < 4; ++s) a[s] = *(const bf16x8*)(abase + s * 32);
    #pragma unroll
    for (int s = 0; s < 4; ++s) a[4 + s] = *(const bf16x8*)(rbase + s * 32);

    const bf16x8* bp = (const bf16x8*)wp;
    int ocol = lane & 15;
    int orow0 = rowTile + (lane >> 4) * 4;

    #pragma unroll
    for (int nt = 0; nt < 8; ++nt) {
        float bv = bias[nt * 16 + ocol];
        f32x4 acc = {bv, bv, bv, bv};
        #pragma unroll
        for (int s = 0; s < 8; ++s) {
            bf16x8 b = bp[(nt * 8 + s) * 64 + lane];
            acc = __builtin_amdgcn_mfma_f32_16x16x32_bf16(a[s], b, acc, 0, 0, 0);
        }
        #pragma unroll
        for (int r = 0; r < 4; ++r) {
            int orow = orow0 + r;
            if (orow < n) {
                float v = fmaxf(acc[r], 0.0f);
                outp[(size_t)orow * FDIM + nt * 16 + ocol] = f2bf(v);
            }
        }
    }
}

// --- segmented global mean pool: 64 nodes/block, batch sorted --------------
// 256 thr = 8 row-lanes x 32 uint2-col-slots. Per graph segment in window:
// stripe-sum rows, LDS-reduce across row-lanes, one atomicAdd per col elem.
__global__ __launch_bounds__(256) void pool_seg_k(
        const unsigned short* __restrict__ h,     // [nN][128] bf16
        const int* __restrict__ batch,
        float* __restrict__ gsum, int* __restrict__ gcnt, int nN) {
    __shared__ int bw[64];
    __shared__ float red[8][32][4];
    int base = blockIdx.x * 64;
    if (base >= nN) return;
    int tid = threadIdx.x;
    int rg = tid >> 5, cs = tid & 31;
    int cnt = min(64, nN - base);
    if (tid < 64) bw[tid] = batch[min(base + tid, nN - 1)];
    __syncthreads();
    int g0 = bw[0], g1 = bw[cnt - 1];

    for (int g = g0; g <= g1; ++g) {
        int s = 0;
        while (s < cnt && bw[s] < g) ++s;
        int e = s;
        while (e < cnt && bw[e] == g) ++e;

        float a0 = 0.f, a1 = 0.f, a2 = 0.f, a3 = 0.f;
        for (int i = s + rg; i < e; i += 8) {
            uint2 v = ((const uint2*)(h + (size_t)(base + i) * FDIM))[cs];
            a0 += bf2f((unsigned short)(v.x & 0xffff));
            a1 += bf2f((unsigned short)(v.x >> 16));
            a2 += bf2f((unsigned short)(v.y & 0xffff));
            a3 += bf2f((unsigned short)(v.y >> 16));
        }
        red[rg][cs][0] = a0; red[rg][cs][1] = a1;
        red[rg][cs][2] = a2; red[rg][cs][3] = a3;
        __syncthreads();
        if (rg == 0 && e > s) {
            #pragma unroll
            for (int r = 1; r < 8; ++r) {
                a0 += red[r][cs][0]; a1 += red[r][cs][1];
                a2 += red[r][cs][2]; a3 += red[r][cs][3];
            }
            float* go = gsum + (size_t)g * FDIM + cs * 4;
            atomicAdd(go + 0, a0);
            atomicAdd(go + 1, a1);
            atomicAdd(go + 2, a2);
            atomicAdd(go + 3, a3);
            if (cs == 0) atomicAdd(&gcnt[g], e - s);
        }
        __syncthreads();
    }
}

// --- head: logits = mean @ wf + bf ; log_softmax ---------------------------
__global__ __launch_bounds__(128) void head_k(const float* __restrict__ gsum,
                                              const int* __restrict__ gcnt,
                                              const float* __restrict__ wf,
                                              const float* __restrict__ bf,
                                              float* __restrict__ out, int nG) {
    int g = blockIdx.x;
    if (g >= nG) return;
    __shared__ float row[FDIM];
    int tid = threadIdx.x;
    float inv = 1.0f / fmaxf((float)gcnt[g], 1.0f);
    row[tid] = gsum[(size_t)g * FDIM + tid] * inv;
    __syncthreads();

    float logit = -1e30f;
    if (tid < 16) {
        logit = bf[tid];
        for (int k = 0; k < FDIM; ++k) logit += row[k] * wf[k * 16 + tid];
    }
    float m = logit;
    for (int off = 8; off >= 1; off >>= 1) m = fmaxf(m, __shfl_xor(m, off, 64));
    float ev = (tid < 16) ? expf(logit - m) : 0.0f;
    float sum = ev;
    for (int off = 8; off >= 1; off >>= 1) sum += __shfl_xor(sum, off, 64);
    if (tid < 16) out[(size_t)g * 16 + tid] = logit - m - logf(sum);
}

extern "C" void kernel_launch(void* const* d_in, const int* in_sizes, int n_in,
                              void* d_out, int out_size, void* d_ws, size_t ws_size,
                              hipStream_t stream) {
    const float* x    = (const float*)d_in[0];
    const int*   ei   = (const int*)d_in[1];
    const int*   batch= (const int*)d_in[2];
    const float* w1l  = (const float*)d_in[3];
    const float* b1   = (const float*)d_in[4];
    const float* w1r  = (const float*)d_in[5];
    const float* w2l  = (const float*)d_in[6];
    const float* b2   = (const float*)d_in[7];
    const float* w2r  = (const float*)d_in[8];
    const float* wf   = (const float*)d_in[9];
    const float* bf   = (const float*)d_in[10];
    float* out = (float*)d_out;

    const int N = in_sizes[0] / FDIM;
    const int E = in_sizes[1] / 2;
    const int G = out_size / 16;
    const int* src = ei;
    const int* dst = ei + E;
    const int NB = (N + 255) / 256;              // <= 256 for scan2_k

    // --- workspace layout ---
    char* ws = (char*)d_ws;
    size_t off = 0;
    auto alloc = [&](size_t bytes) { void* p = ws + off; off = (off + bytes + 255) & ~(size_t)255; return p; };
    unsigned short* xb   = (unsigned short*)alloc((size_t)N * FDIM * 2); // also h2
    unsigned short* aggr = (unsigned short*)alloc((size_t)N * FDIM * 2);
    unsigned short* h1   = (unsigned short*)alloc((size_t)N * FDIM * 2);
    unsigned short* wp1  = (unsigned short*)alloc(8 * 8 * 64 * 8 * 2);
    unsigned short* wp2  = (unsigned short*)alloc(8 * 8 * 64 * 8 * 2);
    int* deg      = (int*)alloc((size_t)N * sizeof(int));
    int* rowstart = (int*)alloc((size_t)N * sizeof(int));
    int* bsum     = (int*)alloc(256 * sizeof(int));
    int* csr      = (int*)alloc((size_t)E * sizeof(int));
    int* rank     = (int*)alloc((size_t)E * sizeof(int));
    float* gsum   = (float*)alloc((size_t)G * FDIM * sizeof(float));
    int*   gcnt   = (int*)alloc((size_t)G * sizeof(int));
    unsigned short* h2 = xb;                      // xb dead by the time h2 is written

    // --- CSR build (atomic-free localized fill) ---
    hipMemsetAsync(deg, 0, (size_t)N * sizeof(int), stream);
    deg_rank_k<<<(E + 255) / 256, 256, 0, stream>>>(dst, deg, rank, E);
    scan1_k<<<NB, 256, 0, stream>>>(deg, rowstart, bsum, N);
    scan2_k<<<1, 256, 0, stream>>>(bsum, NB);
    addoff_k<<<NB, 256, 0, stream>>>(rowstart, bsum, N);
    {
        int rngSize = (N + 7) / 8;
        fill_swz_k<<<2048, 256, 0, stream>>>(src, dst, rowstart, rank, csr, E, rngSize);
    }

    // --- prep: x -> bf16, pack weights, zero pool accumulators ---
    cvt_bf16_k<<<(N * FDIM / 4 + 255) / 256, 256, 0, stream>>>(x, xb, N * FDIM / 4);
    pack_w_k<<<16, 256, 0, stream>>>(w1l, w1r, wp1);
    pack_w_k<<<16, 256, 0, stream>>>(w2l, w2r, wp2);
    hipMemsetAsync(gsum, 0, (size_t)G * FDIM * sizeof(float), stream);
    hipMemsetAsync(gcnt, 0, (size_t)G * sizeof(int), stream);

    // --- layer 1 ---
    gather_mean_k<<<(N + 3) / 4, 256, 0, stream>>>((const uint2*)xb, csr, rowstart, deg,
                                                   (uint2*)aggr, N);
    gemm_mfma_k<<<(N + 63) / 64, 256, 0, stream>>>(aggr, xb, wp1, b1, h1, N);

    // --- layer 2 ---
    gather_mean_k<<<(N + 3) / 4, 256, 0, stream>>>((const uint2*)h1, csr, rowstart, deg,
                                                   (uint2*)aggr, N);
    gemm_mfma_k<<<(N + 63) / 64, 256, 0, stream>>>(aggr, h1, wp2, b2, h2, N);

    // --- pool + head ---
    pool_seg_k<<<(N + 63) / 64, 256, 0, stream>>>(h2, batch, gsum, gcnt, N);
    head_k<<<G, 128, 0, stream>>>(gsum, gcnt, wf, bf, out, G);
}